// Round 7
// baseline (558.531 us; speedup 1.0000x reference)
//
#include <hip/hip_runtime.h>
#include <hip/hip_bf16.h>
#include <hip/hip_fp16.h>

#define N_NODES 100000
#define N_EDGES 1600000
#define N_GRAPHS 512
#define BN_EPS 1e-5f
#define NBKT 196          // buckets of 512 nodes: dst>>9
#define PART_CHUNK 4096

typedef float f32x4 __attribute__((ext_vector_type(4)));
typedef short s16x8 __attribute__((ext_vector_type(8)));

__device__ inline ushort f2bf(float f) {
    union { float f; unsigned u; } v; v.f = f;
    unsigned u = v.u;
    unsigned r = (u + 0x7FFFu + ((u >> 16) & 1u)) >> 16;
    return (ushort)r;
}
__device__ inline float bf2f(ushort h) {
    union { unsigned u; float f; } v; v.u = ((unsigned)h) << 16;
    return v.f;
}

// ---------------- bucket-count histogram (196 coarse bins via LDS) ----------------

__global__ __launch_bounds__(256) void k_bcnt(const int4* __restrict__ dst4, int* __restrict__ bcnt, int E4) {
    __shared__ int h[NBKT];
    int tid = threadIdx.x;
    for (int i = tid; i < NBKT; i += 256) h[i] = 0;
    __syncthreads();
    for (int t = blockIdx.x * 256 + tid; t < E4; t += gridDim.x * 256) {
        int4 d = dst4[t];
        atomicAdd(&h[d.x >> 9], 1);
        atomicAdd(&h[d.y >> 9], 1);
        atomicAdd(&h[d.z >> 9], 1);
        atomicAdd(&h[d.w >> 9], 1);
    }
    __syncthreads();
    for (int i = tid; i < NBKT; i += 256) {
        int v = h[i];
        if (v) atomicAdd(&bcnt[i], v);
    }
}

// ---------------- bucket base scan (tiny) ----------------

__global__ __launch_bounds__(256) void k_bscan(const int* __restrict__ bcnt, int* __restrict__ bbase,
                                               int* __restrict__ gcur) {
    __shared__ int buf[256];
    int tid = threadIdx.x;
    int v = (tid < NBKT) ? bcnt[tid] : 0;
    buf[tid] = v;
    __syncthreads();
    for (int st = 1; st < 256; st <<= 1) {
        int t = (tid >= st) ? buf[tid - st] : 0;
        __syncthreads();
        buf[tid] += t;
        __syncthreads();
    }
    int excl = buf[tid] - v;
    if (tid < NBKT) {
        bbase[tid] = excl;
        gcur[tid] = excl;
    }
    if (tid == NBKT - 1) bbase[NBKT] = excl + v;
}

// ---------------- graph counts via binary search on sorted batch ----------------

__global__ __launch_bounds__(256) void k_gstart(const int* __restrict__ batch, int* __restrict__ gcnt, int N) {
    int g = blockIdx.x * 256 + threadIdx.x;
    if (g >= N_GRAPHS) return;
    auto lb = [&](int key) {
        int lo = 0, hi = N;
        while (lo < hi) {
            int mid = (lo + hi) >> 1;
            if (batch[mid] < key) lo = mid + 1; else hi = mid;
        }
        return lo;
    };
    gcnt[g] = lb(g + 1) - lb(g);
}

// ---------------- x (fp32) -> fp16 copy ----------------

__global__ __launch_bounds__(256) void k_x2h(const float4* __restrict__ x4, uint4* __restrict__ xh, int n8) {
    int i = blockIdx.x * 256 + threadIdx.x;
    if (i >= n8) return;
    float4 a = x4[2 * i], b = x4[2 * i + 1];
    union { uint4 u4; __half h[8]; } cv;
    cv.h[0] = __float2half(a.x); cv.h[1] = __float2half(a.y);
    cv.h[2] = __float2half(a.z); cv.h[3] = __float2half(a.w);
    cv.h[4] = __float2half(b.x); cv.h[5] = __float2half(b.y);
    cv.h[6] = __float2half(b.z); cv.h[7] = __float2half(b.w);
    xh[i] = cv.u4;
}

// ---------------- stage 1: partition edges into 196 coarse buckets ----------------

__global__ __launch_bounds__(256) void k_part(const int* __restrict__ esrc, const int* __restrict__ edst,
                                              int* __restrict__ gcur, unsigned* __restrict__ ebuf, int E) {
    __shared__ int cnt[256], base[256], scn[256];
    __shared__ unsigned ebufL[PART_CHUNK];
    __shared__ int gposL[PART_CHUNK];
    int tid = threadIdx.x;
    int e0 = blockIdx.x * PART_CHUNK;
    int nv = min(PART_CHUNK, E - e0);
    int src[16], dst[16];
    cnt[tid] = 0;
    __syncthreads();
    const int4* s4 = (const int4*)(esrc + e0);
    const int4* d4 = (const int4*)(edst + e0);
    int n4 = nv >> 2;
#pragma unroll
    for (int t = 0; t < 4; ++t) {
        int i4 = t * 256 + tid;
        if (i4 < n4) {
            int4 s = s4[i4];
            int4 d = d4[i4];
            src[t * 4 + 0] = s.x; src[t * 4 + 1] = s.y; src[t * 4 + 2] = s.z; src[t * 4 + 3] = s.w;
            dst[t * 4 + 0] = d.x; dst[t * 4 + 1] = d.y; dst[t * 4 + 2] = d.z; dst[t * 4 + 3] = d.w;
            atomicAdd(&cnt[d.x >> 9], 1);
            atomicAdd(&cnt[d.y >> 9], 1);
            atomicAdd(&cnt[d.z >> 9], 1);
            atomicAdd(&cnt[d.w >> 9], 1);
        } else {
            dst[t * 4 + 0] = -1; dst[t * 4 + 1] = -1; dst[t * 4 + 2] = -1; dst[t * 4 + 3] = -1;
            src[t * 4 + 0] = 0; src[t * 4 + 1] = 0; src[t * 4 + 2] = 0; src[t * 4 + 3] = 0;
        }
    }
    __syncthreads();
    int c = cnt[tid];
    if (tid < NBKT) base[tid] = atomicAdd(&gcur[tid], c);
    scn[tid] = c;
    __syncthreads();
    for (int st = 1; st < 256; st <<= 1) {
        int t = (tid >= st) ? scn[tid - st] : 0;
        __syncthreads();
        scn[tid] += t;
        __syncthreads();
    }
    scn[tid] -= c;
    __syncthreads();
    cnt[tid] = 0;
    __syncthreads();
#pragma unroll
    for (int t = 0; t < 16; ++t) {
        if (dst[t] >= 0) {
            int b = dst[t] >> 9;
            int r = atomicAdd(&cnt[b], 1);
            int s = scn[b] + r;
            ebufL[s] = (((unsigned)(dst[t] & 511)) << 17) | (unsigned)src[t];
            gposL[s] = base[b] + r;
        }
    }
    __syncthreads();
    for (int s = tid; s < nv; s += 256) ebuf[gposL[s]] = ebufL[s];
}

// ---------------- stage 2: per-bucket degree + local scan -> off, then CSR scatter ----------------

__global__ __launch_bounds__(256) void k_bucket(const unsigned* __restrict__ ebuf, const int* __restrict__ bbase,
                                                int* __restrict__ off, int* __restrict__ srcs, int N) {
    __shared__ int degL[512];
    __shared__ int s2[256];
    int b = blockIdx.x;
    int n0 = b << 9;
    int nn = min(512, N - n0);
    int tid = threadIdx.x;
    for (int i = tid; i < nn; i += 256) degL[i] = 0;
    __syncthreads();
    int e0 = bbase[b], e1 = bbase[b + 1];
    for (int i = e0 + tid; i < e1; i += 256) atomicAdd(&degL[ebuf[i] >> 17], 1);
    __syncthreads();
    int a0 = (2 * tid < nn) ? degL[2 * tid] : 0;
    int a1 = (2 * tid + 1 < nn) ? degL[2 * tid + 1] : 0;
    int ps = a0 + a1;
    s2[tid] = ps;
    __syncthreads();
    for (int st = 1; st < 256; st <<= 1) {
        int t = (tid >= st) ? s2[tid - st] : 0;
        __syncthreads();
        s2[tid] += t;
        __syncthreads();
    }
    int excl = s2[tid] - ps;
    if (2 * tid < nn) { off[n0 + 2 * tid] = e0 + excl; degL[2 * tid] = e0 + excl; }
    if (2 * tid + 1 < nn) { off[n0 + 2 * tid + 1] = e0 + excl + a0; degL[2 * tid + 1] = e0 + excl + a0; }
    if (b == NBKT - 1 && tid == 0) off[N] = e1;
    __syncthreads();
    for (int i = e0 + tid; i < e1; i += 256) {
        unsigned p = ebuf[i];
        int dl = (int)(p >> 17);
        int pos = atomicAdd(&degL[dl], 1);
        srcs[pos] = (int)(p & 0x1FFFFu);
    }
}

// ---------------- weight pre-pack (all 6 matrices, one launch) ----------------

struct W6 { const float* w[6]; };

__global__ __launch_bounds__(256) void k_packw6(W6 ws6, ushort* __restrict__ pk) {
    int m = blockIdx.x >> 6;
    int p = (blockIdx.x & 63) * 256 + threadIdx.x;
    const float* W = ws6.w[m];
    ushort* o = pk + (size_t)m * 32768;
    int j = p & 7, l = (p >> 3) & 63, n = (p >> 9) & 7, kc = p >> 12;
    int row = kc * 32 + ((l >> 4) & 3) * 8 + j;
    int col = n * 16 + (l & 15);
    float wv = W[row * 128 + col];
    ushort hi = f2bf(wv);
    ushort lo = f2bf(wv - bf2f(hi));
    o[p] = hi;
    o[16384 + p] = lo;
}

// ---------------- aggregation: pure fp16 gather-sum, fp32 accumulate ----------------
// 4 nodes per wave, 16 lanes/node, 16B (8 ch) per lane, unroll 8

__global__ __launch_bounds__(256) void k_agg(const __half* __restrict__ Xh, float* __restrict__ T,
                                             const int* __restrict__ off, const int* __restrict__ srcs, int N) {
    int gid = blockIdx.x * 256 + threadIdx.x;
    int w = gid >> 6;
    int lane = threadIdx.x & 63;
    int q = lane >> 4;
    int lc = lane & 15;          // channels lc*8 .. lc*8+7
    int node = w * 4 + q;
    if (node >= N) return;

    const uint4* X16 = (const uint4*)Xh;   // one uint4 = 8 halves; row = 16 uint4
    union U { uint4 u4; __half2 h[4]; };

    float2 acc[4];
    {
        U r; r.u4 = X16[(size_t)node * 16 + lc];
#pragma unroll
        for (int k = 0; k < 4; ++k) acc[k] = __half22float2(r.h[k]);
    }

    int s = off[node], e = off[node + 1];
    int j = s;
    for (; j + 7 < e; j += 8) {
        int u0 = srcs[j], u1 = srcs[j + 1], u2 = srcs[j + 2], u3 = srcs[j + 3];
        int u4 = srcs[j + 4], u5 = srcs[j + 5], u6 = srcs[j + 6], u7 = srcs[j + 7];
        U r0, r1, r2, r3, r4, r5, r6, r7;
        r0.u4 = X16[(size_t)u0 * 16 + lc];
        r1.u4 = X16[(size_t)u1 * 16 + lc];
        r2.u4 = X16[(size_t)u2 * 16 + lc];
        r3.u4 = X16[(size_t)u3 * 16 + lc];
        r4.u4 = X16[(size_t)u4 * 16 + lc];
        r5.u4 = X16[(size_t)u5 * 16 + lc];
        r6.u4 = X16[(size_t)u6 * 16 + lc];
        r7.u4 = X16[(size_t)u7 * 16 + lc];
#pragma unroll
        for (int k = 0; k < 4; ++k) {
            float2 f0 = __half22float2(r0.h[k]), f1 = __half22float2(r1.h[k]);
            float2 f2 = __half22float2(r2.h[k]), f3 = __half22float2(r3.h[k]);
            float2 f4 = __half22float2(r4.h[k]), f5 = __half22float2(r5.h[k]);
            float2 f6 = __half22float2(r6.h[k]), f7 = __half22float2(r7.h[k]);
            float2 a01 = make_float2(f0.x + f1.x, f0.y + f1.y);
            float2 a23 = make_float2(f2.x + f3.x, f2.y + f3.y);
            float2 a45 = make_float2(f4.x + f5.x, f4.y + f5.y);
            float2 a67 = make_float2(f6.x + f7.x, f6.y + f7.y);
            acc[k].x += (a01.x + a23.x) + (a45.x + a67.x);
            acc[k].y += (a01.y + a23.y) + (a45.y + a67.y);
        }
    }
    for (; j < e; ++j) {
        U r; r.u4 = X16[(size_t)srcs[j] * 16 + lc];
#pragma unroll
        for (int k = 0; k < 4; ++k) {
            float2 f = __half22float2(r.h[k]);
            acc[k].x += f.x;
            acc[k].y += f.y;
        }
    }

    float4 o0 = make_float4(acc[0].x, acc[0].y, acc[1].x, acc[1].y);
    float4 o1 = make_float4(acc[2].x, acc[2].y, acc[3].x, acc[3].y);
    ((float4*)T)[(size_t)node * 32 + lc * 2] = o0;
    ((float4*)T)[(size_t)node * 32 + lc * 2 + 1] = o1;
}

// ---------------- fused MLP pair: GEMM1 + ReLU -> LDS restage -> GEMM2 + stats; h out fp16 ----------------

__global__ __launch_bounds__(256, 2) void k_mlp_pair(const float* __restrict__ A, __half* __restrict__ out,
        const ushort* __restrict__ pk1, const float* __restrict__ b1,
        const ushort* __restrict__ pk2, const float* __restrict__ b2,
        float* __restrict__ stats, int N) {
    __shared__ float tile[4 * 32 * 128];   // 64 KB
    int tid = threadIdx.x;
    int wid = tid >> 6, l = tid & 63;
    int lr = l & 15, lg = l >> 4;
    int r0 = blockIdx.x * 128 + wid * 32;
    int wbase = wid * 32 * 128;

    const f32x4* A4 = (const f32x4*)A;
    const s16x8* B1 = (const s16x8*)pk1;
    const s16x8* B2 = (const s16x8*)pk2;

    f32x4 acc[2][8];
#pragma unroll
    for (int m = 0; m < 2; ++m)
#pragma unroll
        for (int n = 0; n < 8; ++n) acc[m][n] = (f32x4){0.f, 0.f, 0.f, 0.f};

    // ---- GEMM1 (A from global) ----
#pragma unroll
    for (int kc = 0; kc < 4; ++kc) {
        s16x8 ahi[2], alo[2];
#pragma unroll
        for (int m = 0; m < 2; ++m) {
            int row = min(r0 + m * 16 + lr, N - 1);
            f32x4 v0 = A4[(size_t)row * 32 + kc * 8 + lg * 2];
            f32x4 v1 = A4[(size_t)row * 32 + kc * 8 + lg * 2 + 1];
            float f[8] = {v0.x, v0.y, v0.z, v0.w, v1.x, v1.y, v1.z, v1.w};
#pragma unroll
            for (int j = 0; j < 8; ++j) {
                ushort hi = f2bf(f[j]);
                ahi[m][j] = (short)hi;
                alo[m][j] = (short)f2bf(f[j] - bf2f(hi));
            }
        }
#pragma unroll
        for (int n = 0; n < 8; ++n) {
            int fi = (kc * 8 + n) * 64 + l;
            s16x8 bhi = B1[fi];
            s16x8 blo = B1[2048 + fi];
#pragma unroll
            for (int m = 0; m < 2; ++m) {
                acc[m][n] = __builtin_amdgcn_mfma_f32_16x16x32_bf16(ahi[m], bhi, acc[m][n], 0, 0, 0);
                acc[m][n] = __builtin_amdgcn_mfma_f32_16x16x32_bf16(alo[m], bhi, acc[m][n], 0, 0, 0);
                acc[m][n] = __builtin_amdgcn_mfma_f32_16x16x32_bf16(ahi[m], blo, acc[m][n], 0, 0, 0);
            }
        }
    }

    // ---- epilogue1: bias + ReLU, restage to LDS (swizzled) ----
#pragma unroll
    for (int n = 0; n < 8; ++n) {
        float bv = b1[n * 16 + lr];
        int c4 = n * 4 + (lr >> 2);
        int e = lr & 3;
#pragma unroll
        for (int m = 0; m < 2; ++m) {
#pragma unroll
            for (int i = 0; i < 4; ++i) {
                int row = m * 16 + lg * 4 + i;
                float v = fmaxf(acc[m][n][i] + bv, 0.f);
                tile[wbase + row * 128 + ((c4 ^ (row & 7)) << 2) + e] = v;
            }
        }
    }
    __syncthreads();

    // ---- GEMM2 (A from LDS) ----
#pragma unroll
    for (int m = 0; m < 2; ++m)
#pragma unroll
        for (int n = 0; n < 8; ++n) acc[m][n] = (f32x4){0.f, 0.f, 0.f, 0.f};

#pragma unroll
    for (int kc = 0; kc < 4; ++kc) {
        s16x8 ahi[2], alo[2];
#pragma unroll
        for (int m = 0; m < 2; ++m) {
            int row = m * 16 + lr;
            float f[8];
#pragma unroll
            for (int h = 0; h < 2; ++h) {
                int k4 = kc * 8 + lg * 2 + h;
                f32x4 v = *(const f32x4*)&tile[wbase + row * 128 + ((k4 ^ (row & 7)) << 2)];
                f[h * 4 + 0] = v.x; f[h * 4 + 1] = v.y; f[h * 4 + 2] = v.z; f[h * 4 + 3] = v.w;
            }
#pragma unroll
            for (int j = 0; j < 8; ++j) {
                ushort hi = f2bf(f[j]);
                ahi[m][j] = (short)hi;
                alo[m][j] = (short)f2bf(f[j] - bf2f(hi));
            }
        }
#pragma unroll
        for (int n = 0; n < 8; ++n) {
            int fi = (kc * 8 + n) * 64 + l;
            s16x8 bhi = B2[fi];
            s16x8 blo = B2[2048 + fi];
#pragma unroll
            for (int m = 0; m < 2; ++m) {
                acc[m][n] = __builtin_amdgcn_mfma_f32_16x16x32_bf16(ahi[m], bhi, acc[m][n], 0, 0, 0);
                acc[m][n] = __builtin_amdgcn_mfma_f32_16x16x32_bf16(alo[m], bhi, acc[m][n], 0, 0, 0);
                acc[m][n] = __builtin_amdgcn_mfma_f32_16x16x32_bf16(ahi[m], blo, acc[m][n], 0, 0, 0);
            }
        }
    }
    __syncthreads();

    // ---- epilogue2: bias, stats, fp16 store ----
    float s1[8], s2[8];
#pragma unroll
    for (int n = 0; n < 8; ++n) { s1[n] = 0.f; s2[n] = 0.f; }

#pragma unroll
    for (int n = 0; n < 8; ++n) {
        float bv = b2[n * 16 + lr];
#pragma unroll
        for (int m = 0; m < 2; ++m) {
#pragma unroll
            for (int i = 0; i < 4; ++i) {
                int r = r0 + m * 16 + lg * 4 + i;
                if (r < N) {
                    float v = acc[m][n][i] + bv;
                    s1[n] += v;
                    s2[n] += v * v;
                    out[(size_t)r * 128 + n * 16 + lr] = __float2half(v);
                }
            }
        }
    }

    float* ls = tile;
#pragma unroll
    for (int n = 0; n < 8; ++n) {
        float a = s1[n], b = s2[n];
        a += __shfl_xor(a, 16, 64); a += __shfl_xor(a, 32, 64);
        b += __shfl_xor(b, 16, 64); b += __shfl_xor(b, 32, 64);
        if (lg == 0) {
            ls[wid * 256 + n * 16 + lr] = a;
            ls[wid * 256 + 128 + n * 16 + lr] = b;
        }
    }
    __syncthreads();
    float t = ls[tid] + ls[256 + tid] + ls[512 + tid] + ls[768 + tid];
    atomicAdd(&stats[tid], t);
}

// ---------------- BN apply -> h' (fp16) + segmented mean-pool accumulate ----------------

__global__ __launch_bounds__(128) void k_bnpool(const __half* __restrict__ h, __half* __restrict__ hp,
                                                const float* __restrict__ stats,
                                                const float* __restrict__ gamma, const float* __restrict__ beta,
                                                const int* __restrict__ batch, float* __restrict__ pool,
                                                int loff, int N) {
    int c = threadIdx.x;
    const float invN = 1.0f / (float)N;
    float mean = stats[c] * invN;
    float var = stats[128 + c] * invN - mean * mean;
    float rstd = rsqrtf(var + BN_EPS);
    float gsc = gamma[c] * rstd;
    float bs = beta[c] - mean * gsc;

    int r0 = blockIdx.x * 64;
    int r1 = min(r0 + 64, N);
    float acc = 0.f;
    int curg = -1;
    for (int r = r0; r < r1; ++r) {
        float v = __half2float(h[(size_t)r * 128 + c]);
        float hv = fmaxf(fmaf(v, gsc, bs), 0.f);
        hp[(size_t)r * 128 + c] = __float2half(hv);
        int g = batch[r];
        if (g != curg) {
            if (curg >= 0) atomicAdd(&pool[(size_t)curg * 384 + loff + c], acc);
            curg = g;
            acc = hv;
        } else {
            acc += hv;
        }
    }
    if (curg >= 0) atomicAdd(&pool[(size_t)curg * 384 + loff + c], acc);
}

// ---------------- final linear + row L2-normalize ----------------

__global__ __launch_bounds__(128) void k_final(const float* __restrict__ pool, const int* __restrict__ gcnt,
                                               const float* __restrict__ Wl, const float* __restrict__ bl,
                                               float* __restrict__ out) {
    __shared__ float sh[384];
    __shared__ float red[128];
    int g = blockIdx.x;
    int tid = threadIdx.x;
    float inv = 1.0f / fmaxf((float)gcnt[g], 1.0f);
    for (int t = tid; t < 384; t += 128) sh[t] = pool[(size_t)g * 384 + t] * inv;
    __syncthreads();
    float acc = bl[tid];
    for (int k = 0; k < 384; ++k) acc = fmaf(sh[k], Wl[(size_t)k * 128 + tid], acc);
    red[tid] = acc * acc;
    __syncthreads();
    for (int s = 64; s > 0; s >>= 1) {
        if (tid < s) red[tid] += red[tid + s];
        __syncthreads();
    }
    float norm = sqrtf(red[0]);
    float scale = 1.0f / fmaxf(norm, 1e-12f);
    out[(size_t)g * 128 + tid] = acc * scale;
}

// ---------------- host ----------------

extern "C" void kernel_launch(void* const* d_in, const int* in_sizes, int n_in,
                              void* d_out, int out_size, void* d_ws, size_t ws_size,
                              hipStream_t stream) {
    const float* x = (const float*)d_in[0];
    const int* edge_index = (const int*)d_in[1];
    const int* batch = (const int*)d_in[2];
    const float* Wa[3] = {(const float*)d_in[3], (const float*)d_in[9], (const float*)d_in[15]};
    const float* ba[3] = {(const float*)d_in[4], (const float*)d_in[10], (const float*)d_in[16]};
    const float* Wb[3] = {(const float*)d_in[5], (const float*)d_in[11], (const float*)d_in[17]};
    const float* bb[3] = {(const float*)d_in[6], (const float*)d_in[12], (const float*)d_in[18]};
    const float* gm[3] = {(const float*)d_in[7], (const float*)d_in[13], (const float*)d_in[19]};
    const float* be[3] = {(const float*)d_in[8], (const float*)d_in[14], (const float*)d_in[20]};
    const float* Wl = (const float*)d_in[21];
    const float* bl = (const float*)d_in[22];
    float* out = (float*)d_out;

    const int N = N_NODES, E = N_EDGES, G = N_GRAPHS;
    const int* e_src = edge_index;
    const int* e_dst = edge_index + E;

    char* ws = (char*)d_ws;
    size_t o = 0;
    auto alloc = [&](size_t bytes) -> char* {
        char* p = ws + o;
        o = (o + bytes + 255) & ~(size_t)255;
        return p;
    };
    int* off = (int*)alloc((size_t)(N + 1) * 4);
    int* srcs = (int*)alloc((size_t)E * 4);
    int* gcnt = (int*)alloc((size_t)G * 4);
    int* bcnt = (int*)alloc(256 * 4);
    int* bbase = (int*)alloc(256 * 4);
    int* gcur = (int*)alloc(256 * 4);
    float* stats = (float*)alloc(3 * 256 * 4);
    ushort* wpk = (ushort*)alloc(6 * 32768 * 2);
    float* pool = (float*)alloc((size_t)G * 384 * 4);
    float* T = (float*)alloc((size_t)N * 128 * 4);          // fp32 GIN-sum buffer
    __half* B0 = (__half*)alloc((size_t)N * 128 * 2);       // x16, then h'_l
    __half* B1 = (__half*)alloc((size_t)N * 128 * 2);       // raw h_l
    unsigned* ebuf = (unsigned*)T;   // ebuf dead before T's first write (layer-0 agg)
    (void)ws_size;

    hipMemsetAsync(bcnt, 0, 256 * 4, stream);
    hipMemsetAsync(stats, 0, 3 * 256 * 4, stream);
    hipMemsetAsync(pool, 0, (size_t)G * 384 * 4, stream);

    const int E4 = E / 4;

    k_bcnt<<<256, 256, 0, stream>>>((const int4*)e_dst, bcnt, E4);
    k_bscan<<<1, 256, 0, stream>>>(bcnt, bbase, gcur);
    k_gstart<<<2, 256, 0, stream>>>(batch, gcnt, N);
    k_part<<<(E + PART_CHUNK - 1) / PART_CHUNK, 256, 0, stream>>>(e_src, e_dst, gcur, ebuf, E);
    k_bucket<<<NBKT, 256, 0, stream>>>(ebuf, bbase, off, srcs, N);

    const int n8 = N * 128 / 8;
    k_x2h<<<(n8 + 255) / 256, 256, 0, stream>>>((const float4*)x, (uint4*)B0, n8);

    W6 w6;
    w6.w[0] = Wa[0]; w6.w[1] = Wb[0]; w6.w[2] = Wa[1];
    w6.w[3] = Wb[1]; w6.w[4] = Wa[2]; w6.w[5] = Wb[2];
    k_packw6<<<384, 256, 0, stream>>>(w6, wpk);

    const int aggBlocks = ((N + 3) / 4 * 64 + 255) / 256;
    const int mlpBlocks = (N + 127) / 128;
    const int bnBlocks = (N + 63) / 64;

    for (int l = 0; l < 3; ++l) {
        float* statsl = stats + l * 256;
        // B0 holds the layer input (x16 for l=0, h'_{l} thereafter); safe to
        // overwrite B0 with h'_{l+1} after agg has consumed it (stream-ordered).
        k_agg<<<aggBlocks, 256, 0, stream>>>(B0, T, off, srcs, N);
        k_mlp_pair<<<mlpBlocks, 256, 0, stream>>>(T, B1, wpk + (size_t)(2 * l) * 32768, ba[l],
                                                  wpk + (size_t)(2 * l + 1) * 32768, bb[l], statsl, N);
        k_bnpool<<<bnBlocks, 128, 0, stream>>>(B1, B0, statsl, gm[l], be[l], batch, pool, l * 128, N);
    }

    k_final<<<G, 128, 0, stream>>>(pool, gcnt, Wl, bl, out);
}

// Round 8
// 502.969 us; speedup vs baseline: 1.1105x; 1.1105x over previous
//
#include <hip/hip_runtime.h>
#include <hip/hip_bf16.h>
#include <hip/hip_fp16.h>

#define N_NODES 100000
#define N_EDGES 1600000
#define N_GRAPHS 512
#define BN_EPS 1e-5f
#define NBKT 196          // buckets of 512 nodes: dst>>9
#define PART_CHUNK 4096

typedef float f32x4 __attribute__((ext_vector_type(4)));
typedef _Float16 f16x8 __attribute__((ext_vector_type(8)));

// ---------------- bucket-count histogram (196 coarse bins via LDS) ----------------

__global__ __launch_bounds__(256) void k_bcnt(const int4* __restrict__ dst4, int* __restrict__ bcnt, int E4) {
    __shared__ int h[NBKT];
    int tid = threadIdx.x;
    for (int i = tid; i < NBKT; i += 256) h[i] = 0;
    __syncthreads();
    for (int t = blockIdx.x * 256 + tid; t < E4; t += gridDim.x * 256) {
        int4 d = dst4[t];
        atomicAdd(&h[d.x >> 9], 1);
        atomicAdd(&h[d.y >> 9], 1);
        atomicAdd(&h[d.z >> 9], 1);
        atomicAdd(&h[d.w >> 9], 1);
    }
    __syncthreads();
    for (int i = tid; i < NBKT; i += 256) {
        int v = h[i];
        if (v) atomicAdd(&bcnt[i], v);
    }
}

// ---------------- bucket base scan (tiny) ----------------

__global__ __launch_bounds__(256) void k_bscan(const int* __restrict__ bcnt, int* __restrict__ bbase,
                                               int* __restrict__ gcur) {
    __shared__ int buf[256];
    int tid = threadIdx.x;
    int v = (tid < NBKT) ? bcnt[tid] : 0;
    buf[tid] = v;
    __syncthreads();
    for (int st = 1; st < 256; st <<= 1) {
        int t = (tid >= st) ? buf[tid - st] : 0;
        __syncthreads();
        buf[tid] += t;
        __syncthreads();
    }
    int excl = buf[tid] - v;
    if (tid < NBKT) {
        bbase[tid] = excl;
        gcur[tid] = excl;
    }
    if (tid == NBKT - 1) bbase[NBKT] = excl + v;
}

// ---------------- graph counts via binary search on sorted batch ----------------

__global__ __launch_bounds__(256) void k_gstart(const int* __restrict__ batch, int* __restrict__ gcnt, int N) {
    int g = blockIdx.x * 256 + threadIdx.x;
    if (g >= N_GRAPHS) return;
    auto lb = [&](int key) {
        int lo = 0, hi = N;
        while (lo < hi) {
            int mid = (lo + hi) >> 1;
            if (batch[mid] < key) lo = mid + 1; else hi = mid;
        }
        return lo;
    };
    gcnt[g] = lb(g + 1) - lb(g);
}

// ---------------- x (fp32) -> fp16 copy ----------------

__global__ __launch_bounds__(256) void k_x2h(const float4* __restrict__ x4, uint4* __restrict__ xh, int n8) {
    int i = blockIdx.x * 256 + threadIdx.x;
    if (i >= n8) return;
    float4 a = x4[2 * i], b = x4[2 * i + 1];
    union { uint4 u4; __half h[8]; } cv;
    cv.h[0] = __float2half(a.x); cv.h[1] = __float2half(a.y);
    cv.h[2] = __float2half(a.z); cv.h[3] = __float2half(a.w);
    cv.h[4] = __float2half(b.x); cv.h[5] = __float2half(b.y);
    cv.h[6] = __float2half(b.z); cv.h[7] = __float2half(b.w);
    xh[i] = cv.u4;
}

// ---------------- stage 1: partition edges into 196 coarse buckets ----------------

__global__ __launch_bounds__(256) void k_part(const int* __restrict__ esrc, const int* __restrict__ edst,
                                              int* __restrict__ gcur, unsigned* __restrict__ ebuf, int E) {
    __shared__ int cnt[256], base[256], scn[256];
    __shared__ unsigned ebufL[PART_CHUNK];
    __shared__ int gposL[PART_CHUNK];
    int tid = threadIdx.x;
    int e0 = blockIdx.x * PART_CHUNK;
    int nv = min(PART_CHUNK, E - e0);
    int src[16], dst[16];
    cnt[tid] = 0;
    __syncthreads();
    const int4* s4 = (const int4*)(esrc + e0);
    const int4* d4 = (const int4*)(edst + e0);
    int n4 = nv >> 2;
#pragma unroll
    for (int t = 0; t < 4; ++t) {
        int i4 = t * 256 + tid;
        if (i4 < n4) {
            int4 s = s4[i4];
            int4 d = d4[i4];
            src[t * 4 + 0] = s.x; src[t * 4 + 1] = s.y; src[t * 4 + 2] = s.z; src[t * 4 + 3] = s.w;
            dst[t * 4 + 0] = d.x; dst[t * 4 + 1] = d.y; dst[t * 4 + 2] = d.z; dst[t * 4 + 3] = d.w;
            atomicAdd(&cnt[d.x >> 9], 1);
            atomicAdd(&cnt[d.y >> 9], 1);
            atomicAdd(&cnt[d.z >> 9], 1);
            atomicAdd(&cnt[d.w >> 9], 1);
        } else {
            dst[t * 4 + 0] = -1; dst[t * 4 + 1] = -1; dst[t * 4 + 2] = -1; dst[t * 4 + 3] = -1;
            src[t * 4 + 0] = 0; src[t * 4 + 1] = 0; src[t * 4 + 2] = 0; src[t * 4 + 3] = 0;
        }
    }
    __syncthreads();
    int c = cnt[tid];
    if (tid < NBKT) base[tid] = atomicAdd(&gcur[tid], c);
    scn[tid] = c;
    __syncthreads();
    for (int st = 1; st < 256; st <<= 1) {
        int t = (tid >= st) ? scn[tid - st] : 0;
        __syncthreads();
        scn[tid] += t;
        __syncthreads();
    }
    scn[tid] -= c;
    __syncthreads();
    cnt[tid] = 0;
    __syncthreads();
#pragma unroll
    for (int t = 0; t < 16; ++t) {
        if (dst[t] >= 0) {
            int b = dst[t] >> 9;
            int r = atomicAdd(&cnt[b], 1);
            int s = scn[b] + r;
            ebufL[s] = (((unsigned)(dst[t] & 511)) << 17) | (unsigned)src[t];
            gposL[s] = base[b] + r;
        }
    }
    __syncthreads();
    for (int s = tid; s < nv; s += 256) ebuf[gposL[s]] = ebufL[s];
}

// ---------------- stage 2: per-bucket degree + local scan -> off, then CSR scatter ----------------

__global__ __launch_bounds__(256) void k_bucket(const unsigned* __restrict__ ebuf, const int* __restrict__ bbase,
                                                int* __restrict__ off, int* __restrict__ srcs, int N) {
    __shared__ int degL[512];
    __shared__ int s2[256];
    int b = blockIdx.x;
    int n0 = b << 9;
    int nn = min(512, N - n0);
    int tid = threadIdx.x;
    for (int i = tid; i < nn; i += 256) degL[i] = 0;
    __syncthreads();
    int e0 = bbase[b], e1 = bbase[b + 1];
    for (int i = e0 + tid; i < e1; i += 256) atomicAdd(&degL[ebuf[i] >> 17], 1);
    __syncthreads();
    int a0 = (2 * tid < nn) ? degL[2 * tid] : 0;
    int a1 = (2 * tid + 1 < nn) ? degL[2 * tid + 1] : 0;
    int ps = a0 + a1;
    s2[tid] = ps;
    __syncthreads();
    for (int st = 1; st < 256; st <<= 1) {
        int t = (tid >= st) ? s2[tid - st] : 0;
        __syncthreads();
        s2[tid] += t;
        __syncthreads();
    }
    int excl = s2[tid] - ps;
    if (2 * tid < nn) { off[n0 + 2 * tid] = e0 + excl; degL[2 * tid] = e0 + excl; }
    if (2 * tid + 1 < nn) { off[n0 + 2 * tid + 1] = e0 + excl + a0; degL[2 * tid + 1] = e0 + excl + a0; }
    if (b == NBKT - 1 && tid == 0) off[N] = e1;
    __syncthreads();
    for (int i = e0 + tid; i < e1; i += 256) {
        unsigned p = ebuf[i];
        int dl = (int)(p >> 17);
        int pos = atomicAdd(&degL[dl], 1);
        srcs[pos] = (int)(p & 0x1FFFFu);
    }
}

// ---------------- weight pre-pack (fp16 single, all 6 matrices) ----------------
// packed index p = ((kc*8 + n)*64 + l)*8 + j  ->  W[kc*32 + ((l>>4)&3)*8 + j][n*16 + (l&15)]

struct W6 { const float* w[6]; };

__global__ __launch_bounds__(256) void k_packw6(W6 ws6, ushort* __restrict__ pk) {
    int m = blockIdx.x >> 6;
    int p = (blockIdx.x & 63) * 256 + threadIdx.x;   // 0..16383
    const float* W = ws6.w[m];
    ushort* o = pk + (size_t)m * 16384;
    int j = p & 7, l = (p >> 3) & 63, n = (p >> 9) & 7, kc = p >> 12;
    int row = kc * 32 + ((l >> 4) & 3) * 8 + j;
    int col = n * 16 + (l & 15);
    union { _Float16 h; ushort u; } cv;
    cv.h = (_Float16)W[row * 128 + col];
    o[p] = cv.u;
}

// ---------------- aggregation: pure fp16 gather-sum, fp32 accumulate ----------------
// 4 nodes per wave, 16 lanes/node, 16B (8 ch) per lane, unroll 8

__global__ __launch_bounds__(256) void k_agg(const __half* __restrict__ Xh, float* __restrict__ T,
                                             const int* __restrict__ off, const int* __restrict__ srcs, int N) {
    int gid = blockIdx.x * 256 + threadIdx.x;
    int w = gid >> 6;
    int lane = threadIdx.x & 63;
    int q = lane >> 4;
    int lc = lane & 15;          // channels lc*8 .. lc*8+7
    int node = w * 4 + q;
    if (node >= N) return;

    const uint4* X16 = (const uint4*)Xh;   // one uint4 = 8 halves; row = 16 uint4
    union U { uint4 u4; __half2 h[4]; };

    float2 acc[4];
    {
        U r; r.u4 = X16[(size_t)node * 16 + lc];
#pragma unroll
        for (int k = 0; k < 4; ++k) acc[k] = __half22float2(r.h[k]);
    }

    int s = off[node], e = off[node + 1];
    int j = s;
    for (; j + 7 < e; j += 8) {
        int u0 = srcs[j], u1 = srcs[j + 1], u2 = srcs[j + 2], u3 = srcs[j + 3];
        int u4 = srcs[j + 4], u5 = srcs[j + 5], u6 = srcs[j + 6], u7 = srcs[j + 7];
        U r0, r1, r2, r3, r4, r5, r6, r7;
        r0.u4 = X16[(size_t)u0 * 16 + lc];
        r1.u4 = X16[(size_t)u1 * 16 + lc];
        r2.u4 = X16[(size_t)u2 * 16 + lc];
        r3.u4 = X16[(size_t)u3 * 16 + lc];
        r4.u4 = X16[(size_t)u4 * 16 + lc];
        r5.u4 = X16[(size_t)u5 * 16 + lc];
        r6.u4 = X16[(size_t)u6 * 16 + lc];
        r7.u4 = X16[(size_t)u7 * 16 + lc];
#pragma unroll
        for (int k = 0; k < 4; ++k) {
            float2 f0 = __half22float2(r0.h[k]), f1 = __half22float2(r1.h[k]);
            float2 f2 = __half22float2(r2.h[k]), f3 = __half22float2(r3.h[k]);
            float2 f4 = __half22float2(r4.h[k]), f5 = __half22float2(r5.h[k]);
            float2 f6 = __half22float2(r6.h[k]), f7 = __half22float2(r7.h[k]);
            float2 a01 = make_float2(f0.x + f1.x, f0.y + f1.y);
            float2 a23 = make_float2(f2.x + f3.x, f2.y + f3.y);
            float2 a45 = make_float2(f4.x + f5.x, f4.y + f5.y);
            float2 a67 = make_float2(f6.x + f7.x, f6.y + f7.y);
            acc[k].x += (a01.x + a23.x) + (a45.x + a67.x);
            acc[k].y += (a01.y + a23.y) + (a45.y + a67.y);
        }
    }
    for (; j < e; ++j) {
        U r; r.u4 = X16[(size_t)srcs[j] * 16 + lc];
#pragma unroll
        for (int k = 0; k < 4; ++k) {
            float2 f = __half22float2(r.h[k]);
            acc[k].x += f.x;
            acc[k].y += f.y;
        }
    }

    float4 o0 = make_float4(acc[0].x, acc[0].y, acc[1].x, acc[1].y);
    float4 o1 = make_float4(acc[2].x, acc[2].y, acc[3].x, acc[3].y);
    ((float4*)T)[(size_t)node * 32 + lc * 2] = o0;
    ((float4*)T)[(size_t)node * 32 + lc * 2 + 1] = o1;
}

// ---------------- fused MLP pair, fp16 MFMA: GEMM1+ReLU -> fp16 LDS (swizzled) -> GEMM2 + stats ----------------
// per-wave 32-row tile; LDS fp16 [32][128], 16B-chunk swizzle: chunk' = chunk ^ (row & 15)

__global__ __launch_bounds__(256, 4) void k_mlp_pair(const float* __restrict__ A, __half* __restrict__ out,
        const ushort* __restrict__ pk1, const float* __restrict__ b1,
        const ushort* __restrict__ pk2, const float* __restrict__ b2,
        float* __restrict__ stats, int N) {
    __shared__ _Float16 tile[4 * 32 * 128];   // 32 KB
    int tid = threadIdx.x;
    int wid = tid >> 6, l = tid & 63;
    int lr = l & 15, lg = l >> 4;
    int r0 = blockIdx.x * 128 + wid * 32;
    int wbase = wid * 32 * 128;

    const f32x4* A4 = (const f32x4*)A;
    const f16x8* B1 = (const f16x8*)pk1;
    const f16x8* B2 = (const f16x8*)pk2;

    f32x4 acc[2][8];
#pragma unroll
    for (int m = 0; m < 2; ++m)
#pragma unroll
        for (int n = 0; n < 8; ++n) acc[m][n] = (f32x4){0.f, 0.f, 0.f, 0.f};

    // ---- GEMM1 (A from global fp32, cvt to fp16) ----
#pragma unroll
    for (int kc = 0; kc < 4; ++kc) {
        f16x8 af[2];
#pragma unroll
        for (int m = 0; m < 2; ++m) {
            int row = min(r0 + m * 16 + lr, N - 1);
            f32x4 v0 = A4[(size_t)row * 32 + kc * 8 + lg * 2];
            f32x4 v1 = A4[(size_t)row * 32 + kc * 8 + lg * 2 + 1];
            af[m][0] = (_Float16)v0.x; af[m][1] = (_Float16)v0.y;
            af[m][2] = (_Float16)v0.z; af[m][3] = (_Float16)v0.w;
            af[m][4] = (_Float16)v1.x; af[m][5] = (_Float16)v1.y;
            af[m][6] = (_Float16)v1.z; af[m][7] = (_Float16)v1.w;
        }
#pragma unroll
        for (int n = 0; n < 8; ++n) {
            f16x8 bf = B1[(kc * 8 + n) * 64 + l];
#pragma unroll
            for (int m = 0; m < 2; ++m)
                acc[m][n] = __builtin_amdgcn_mfma_f32_16x16x32_f16(af[m], bf, acc[m][n], 0, 0, 0);
        }
    }

    // ---- epilogue1: bias + ReLU, fp16 restage to LDS (swizzled 16B chunks) ----
#pragma unroll
    for (int n = 0; n < 8; ++n) {
        float bv = b1[n * 16 + lr];
        int col = n * 16 + lr;
        int chunk = col >> 3;
        int lo3 = col & 7;
#pragma unroll
        for (int m = 0; m < 2; ++m) {
#pragma unroll
            for (int i = 0; i < 4; ++i) {
                int row = m * 16 + lg * 4 + i;
                float v = fmaxf(acc[m][n][i] + bv, 0.f);
                tile[wbase + row * 128 + ((chunk ^ (row & 15)) << 3) + lo3] = (_Float16)v;
            }
        }
    }
    __syncthreads();

    // ---- GEMM2 (A from LDS, already fp16) ----
#pragma unroll
    for (int m = 0; m < 2; ++m)
#pragma unroll
        for (int n = 0; n < 8; ++n) acc[m][n] = (f32x4){0.f, 0.f, 0.f, 0.f};

#pragma unroll
    for (int kc = 0; kc < 4; ++kc) {
        f16x8 af[2];
#pragma unroll
        for (int m = 0; m < 2; ++m) {
            int row = m * 16 + lr;
            af[m] = *(const f16x8*)&tile[wbase + row * 128 + (((kc * 4 + lg) ^ (row & 15)) << 3)];
        }
#pragma unroll
        for (int n = 0; n < 8; ++n) {
            f16x8 bf = B2[(kc * 8 + n) * 64 + l];
#pragma unroll
            for (int m = 0; m < 2; ++m)
                acc[m][n] = __builtin_amdgcn_mfma_f32_16x16x32_f16(af[m], bf, acc[m][n], 0, 0, 0);
        }
    }
    __syncthreads();   // LDS reads done before stats overlay

    // ---- epilogue2: bias, stats, fp16 store ----
    float s1[8], s2[8];
#pragma unroll
    for (int n = 0; n < 8; ++n) { s1[n] = 0.f; s2[n] = 0.f; }

#pragma unroll
    for (int n = 0; n < 8; ++n) {
        float bv = b2[n * 16 + lr];
#pragma unroll
        for (int m = 0; m < 2; ++m) {
#pragma unroll
            for (int i = 0; i < 4; ++i) {
                int r = r0 + m * 16 + lg * 4 + i;
                if (r < N) {
                    float v = acc[m][n][i] + bv;
                    s1[n] += v;
                    s2[n] += v * v;
                    out[(size_t)r * 128 + n * 16 + lr] = __float2half(v);
                }
            }
        }
    }

    float* ls = (float*)tile;   // overlay [4][256] floats = 4 KB
#pragma unroll
    for (int n = 0; n < 8; ++n) {
        float a = s1[n], b = s2[n];
        a += __shfl_xor(a, 16, 64); a += __shfl_xor(a, 32, 64);
        b += __shfl_xor(b, 16, 64); b += __shfl_xor(b, 32, 64);
        if (lg == 0) {
            ls[wid * 256 + n * 16 + lr] = a;
            ls[wid * 256 + 128 + n * 16 + lr] = b;
        }
    }
    __syncthreads();
    float t = ls[tid] + ls[256 + tid] + ls[512 + tid] + ls[768 + tid];
    atomicAdd(&stats[tid], t);
}

// ---------------- BN apply -> h' (fp16) + segmented mean-pool accumulate ----------------

__global__ __launch_bounds__(128) void k_bnpool(const __half* __restrict__ h, __half* __restrict__ hp,
                                                const float* __restrict__ stats,
                                                const float* __restrict__ gamma, const float* __restrict__ beta,
                                                const int* __restrict__ batch, float* __restrict__ pool,
                                                int loff, int N) {
    int c = threadIdx.x;
    const float invN = 1.0f / (float)N;
    float mean = stats[c] * invN;
    float var = stats[128 + c] * invN - mean * mean;
    float rstd = rsqrtf(var + BN_EPS);
    float gsc = gamma[c] * rstd;
    float bs = beta[c] - mean * gsc;

    int r0 = blockIdx.x * 64;
    int r1 = min(r0 + 64, N);
    float acc = 0.f;
    int curg = -1;
    for (int r = r0; r < r1; ++r) {
        float v = __half2float(h[(size_t)r * 128 + c]);
        float hv = fmaxf(fmaf(v, gsc, bs), 0.f);
        hp[(size_t)r * 128 + c] = __float2half(hv);
        int g = batch[r];
        if (g != curg) {
            if (curg >= 0) atomicAdd(&pool[(size_t)curg * 384 + loff + c], acc);
            curg = g;
            acc = hv;
        } else {
            acc += hv;
        }
    }
    if (curg >= 0) atomicAdd(&pool[(size_t)curg * 384 + loff + c], acc);
}

// ---------------- final linear + row L2-normalize ----------------

__global__ __launch_bounds__(128) void k_final(const float* __restrict__ pool, const int* __restrict__ gcnt,
                                               const float* __restrict__ Wl, const float* __restrict__ bl,
                                               float* __restrict__ out) {
    __shared__ float sh[384];
    __shared__ float red[128];
    int g = blockIdx.x;
    int tid = threadIdx.x;
    float inv = 1.0f / fmaxf((float)gcnt[g], 1.0f);
    for (int t = tid; t < 384; t += 128) sh[t] = pool[(size_t)g * 384 + t] * inv;
    __syncthreads();
    float acc = bl[tid];
    for (int k = 0; k < 384; ++k) acc = fmaf(sh[k], Wl[(size_t)k * 128 + tid], acc);
    red[tid] = acc * acc;
    __syncthreads();
    for (int s = 64; s > 0; s >>= 1) {
        if (tid < s) red[tid] += red[tid + s];
        __syncthreads();
    }
    float norm = sqrtf(red[0]);
    float scale = 1.0f / fmaxf(norm, 1e-12f);
    out[(size_t)g * 128 + tid] = acc * scale;
}

// ---------------- host ----------------

extern "C" void kernel_launch(void* const* d_in, const int* in_sizes, int n_in,
                              void* d_out, int out_size, void* d_ws, size_t ws_size,
                              hipStream_t stream) {
    const float* x = (const float*)d_in[0];
    const int* edge_index = (const int*)d_in[1];
    const int* batch = (const int*)d_in[2];
    const float* Wa[3] = {(const float*)d_in[3], (const float*)d_in[9], (const float*)d_in[15]};
    const float* ba[3] = {(const float*)d_in[4], (const float*)d_in[10], (const float*)d_in[16]};
    const float* Wb[3] = {(const float*)d_in[5], (const float*)d_in[11], (const float*)d_in[17]};
    const float* bb[3] = {(const float*)d_in[6], (const float*)d_in[12], (const float*)d_in[18]};
    const float* gm[3] = {(const float*)d_in[7], (const float*)d_in[13], (const float*)d_in[19]};
    const float* be[3] = {(const float*)d_in[8], (const float*)d_in[14], (const float*)d_in[20]};
    const float* Wl = (const float*)d_in[21];
    const float* bl = (const float*)d_in[22];
    float* out = (float*)d_out;

    const int N = N_NODES, E = N_EDGES, G = N_GRAPHS;
    const int* e_src = edge_index;
    const int* e_dst = edge_index + E;

    char* ws = (char*)d_ws;
    size_t o = 0;
    auto alloc = [&](size_t bytes) -> char* {
        char* p = ws + o;
        o = (o + bytes + 255) & ~(size_t)255;
        return p;
    };
    int* off = (int*)alloc((size_t)(N + 1) * 4);
    int* srcs = (int*)alloc((size_t)E * 4);
    int* gcnt = (int*)alloc((size_t)G * 4);
    int* bcnt = (int*)alloc(256 * 4);
    int* bbase = (int*)alloc(256 * 4);
    int* gcur = (int*)alloc(256 * 4);
    float* stats = (float*)alloc(3 * 256 * 4);
    ushort* wpk = (ushort*)alloc(6 * 16384 * 2);            // fp16 packed weights
    float* pool = (float*)alloc((size_t)G * 384 * 4);
    float* T = (float*)alloc((size_t)N * 128 * 4);          // fp32 GIN-sum buffer
    __half* B0 = (__half*)alloc((size_t)N * 128 * 2);       // x16, then h'_l
    __half* B1 = (__half*)alloc((size_t)N * 128 * 2);       // raw h_l
    unsigned* ebuf = (unsigned*)T;   // ebuf dead before T's first write (layer-0 agg)
    (void)ws_size;

    hipMemsetAsync(bcnt, 0, 256 * 4, stream);
    hipMemsetAsync(stats, 0, 3 * 256 * 4, stream);
    hipMemsetAsync(pool, 0, (size_t)G * 384 * 4, stream);

    const int E4 = E / 4;

    k_bcnt<<<256, 256, 0, stream>>>((const int4*)e_dst, bcnt, E4);
    k_bscan<<<1, 256, 0, stream>>>(bcnt, bbase, gcur);
    k_gstart<<<2, 256, 0, stream>>>(batch, gcnt, N);
    k_part<<<(E + PART_CHUNK - 1) / PART_CHUNK, 256, 0, stream>>>(e_src, e_dst, gcur, ebuf, E);
    k_bucket<<<NBKT, 256, 0, stream>>>(ebuf, bbase, off, srcs, N);

    const int n8 = N * 128 / 8;
    k_x2h<<<(n8 + 255) / 256, 256, 0, stream>>>((const float4*)x, (uint4*)B0, n8);

    W6 w6;
    w6.w[0] = Wa[0]; w6.w[1] = Wb[0]; w6.w[2] = Wa[1];
    w6.w[3] = Wb[1]; w6.w[4] = Wa[2]; w6.w[5] = Wb[2];
    k_packw6<<<384, 256, 0, stream>>>(w6, wpk);

    const int aggBlocks = ((N + 3) / 4 * 64 + 255) / 256;
    const int mlpBlocks = (N + 127) / 128;
    const int bnBlocks = (N + 63) / 64;

    for (int l = 0; l < 3; ++l) {
        float* statsl = stats + l * 256;
        k_agg<<<aggBlocks, 256, 0, stream>>>(B0, T, off, srcs, N);
        k_mlp_pair<<<mlpBlocks, 256, 0, stream>>>(T, B1, wpk + (size_t)(2 * l) * 16384, ba[l],
                                                  wpk + (size_t)(2 * l + 1) * 16384, bb[l], statsl, N);
        k_bnpool<<<bnBlocks, 128, 0, stream>>>(B1, B0, statsl, gm[l], be[l], batch, pool, l * 128, N);
    }

    k_final<<<G, 128, 0, stream>>>(pool, gcnt, Wl, bl, out);
}

// Round 9
// 454.382 us; speedup vs baseline: 1.2292x; 1.1069x over previous
//
#include <hip/hip_runtime.h>
#include <hip/hip_bf16.h>
#include <hip/hip_fp16.h>

#define N_NODES 100000
#define N_EDGES 1600000
#define N_GRAPHS 512
#define BN_EPS 1e-5f
#define NBKT 196          // buckets of 512 nodes: dst>>9
#define PART_CHUNK 4096

typedef float f32x4 __attribute__((ext_vector_type(4)));
typedef _Float16 f16x8 __attribute__((ext_vector_type(8)));

// ---------------- bucket-count histogram (196 coarse bins via LDS) ----------------

__global__ __launch_bounds__(256) void k_bcnt(const int4* __restrict__ dst4, int* __restrict__ bcnt, int E4) {
    __shared__ int h[NBKT];
    int tid = threadIdx.x;
    for (int i = tid; i < NBKT; i += 256) h[i] = 0;
    __syncthreads();
    for (int t = blockIdx.x * 256 + tid; t < E4; t += gridDim.x * 256) {
        int4 d = dst4[t];
        atomicAdd(&h[d.x >> 9], 1);
        atomicAdd(&h[d.y >> 9], 1);
        atomicAdd(&h[d.z >> 9], 1);
        atomicAdd(&h[d.w >> 9], 1);
    }
    __syncthreads();
    for (int i = tid; i < NBKT; i += 256) {
        int v = h[i];
        if (v) atomicAdd(&bcnt[i], v);
    }
}

// ---------------- bucket base scan (tiny) ----------------

__global__ __launch_bounds__(256) void k_bscan(const int* __restrict__ bcnt, int* __restrict__ bbase,
                                               int* __restrict__ gcur) {
    __shared__ int buf[256];
    int tid = threadIdx.x;
    int v = (tid < NBKT) ? bcnt[tid] : 0;
    buf[tid] = v;
    __syncthreads();
    for (int st = 1; st < 256; st <<= 1) {
        int t = (tid >= st) ? buf[tid - st] : 0;
        __syncthreads();
        buf[tid] += t;
        __syncthreads();
    }
    int excl = buf[tid] - v;
    if (tid < NBKT) {
        bbase[tid] = excl;
        gcur[tid] = excl;
    }
    if (tid == NBKT - 1) bbase[NBKT] = excl + v;
}

// ---------------- graph counts via binary search on sorted batch ----------------

__global__ __launch_bounds__(256) void k_gstart(const int* __restrict__ batch, int* __restrict__ gcnt, int N) {
    int g = blockIdx.x * 256 + threadIdx.x;
    if (g >= N_GRAPHS) return;
    auto lb = [&](int key) {
        int lo = 0, hi = N;
        while (lo < hi) {
            int mid = (lo + hi) >> 1;
            if (batch[mid] < key) lo = mid + 1; else hi = mid;
        }
        return lo;
    };
    gcnt[g] = lb(g + 1) - lb(g);
}

// ---------------- x (fp32) -> fp16 copy ----------------

__global__ __launch_bounds__(256) void k_x2h(const float4* __restrict__ x4, uint4* __restrict__ xh, int n8) {
    int i = blockIdx.x * 256 + threadIdx.x;
    if (i >= n8) return;
    float4 a = x4[2 * i], b = x4[2 * i + 1];
    union { uint4 u4; __half h[8]; } cv;
    cv.h[0] = __float2half(a.x); cv.h[1] = __float2half(a.y);
    cv.h[2] = __float2half(a.z); cv.h[3] = __float2half(a.w);
    cv.h[4] = __float2half(b.x); cv.h[5] = __float2half(b.y);
    cv.h[6] = __float2half(b.z); cv.h[7] = __float2half(b.w);
    xh[i] = cv.u4;
}

// ---------------- stage 1: partition edges into 196 coarse buckets ----------------

__global__ __launch_bounds__(256) void k_part(const int* __restrict__ esrc, const int* __restrict__ edst,
                                              int* __restrict__ gcur, unsigned* __restrict__ ebuf, int E) {
    __shared__ int cnt[256], base[256], scn[256];
    __shared__ unsigned ebufL[PART_CHUNK];
    __shared__ int gposL[PART_CHUNK];
    int tid = threadIdx.x;
    int e0 = blockIdx.x * PART_CHUNK;
    int nv = min(PART_CHUNK, E - e0);
    int src[16], dst[16];
    cnt[tid] = 0;
    __syncthreads();
    const int4* s4 = (const int4*)(esrc + e0);
    const int4* d4 = (const int4*)(edst + e0);
    int n4 = nv >> 2;
#pragma unroll
    for (int t = 0; t < 4; ++t) {
        int i4 = t * 256 + tid;
        if (i4 < n4) {
            int4 s = s4[i4];
            int4 d = d4[i4];
            src[t * 4 + 0] = s.x; src[t * 4 + 1] = s.y; src[t * 4 + 2] = s.z; src[t * 4 + 3] = s.w;
            dst[t * 4 + 0] = d.x; dst[t * 4 + 1] = d.y; dst[t * 4 + 2] = d.z; dst[t * 4 + 3] = d.w;
            atomicAdd(&cnt[d.x >> 9], 1);
            atomicAdd(&cnt[d.y >> 9], 1);
            atomicAdd(&cnt[d.z >> 9], 1);
            atomicAdd(&cnt[d.w >> 9], 1);
        } else {
            dst[t * 4 + 0] = -1; dst[t * 4 + 1] = -1; dst[t * 4 + 2] = -1; dst[t * 4 + 3] = -1;
            src[t * 4 + 0] = 0; src[t * 4 + 1] = 0; src[t * 4 + 2] = 0; src[t * 4 + 3] = 0;
        }
    }
    __syncthreads();
    int c = cnt[tid];
    if (tid < NBKT) base[tid] = atomicAdd(&gcur[tid], c);
    scn[tid] = c;
    __syncthreads();
    for (int st = 1; st < 256; st <<= 1) {
        int t = (tid >= st) ? scn[tid - st] : 0;
        __syncthreads();
        scn[tid] += t;
        __syncthreads();
    }
    scn[tid] -= c;
    __syncthreads();
    cnt[tid] = 0;
    __syncthreads();
#pragma unroll
    for (int t = 0; t < 16; ++t) {
        if (dst[t] >= 0) {
            int b = dst[t] >> 9;
            int r = atomicAdd(&cnt[b], 1);
            int s = scn[b] + r;
            ebufL[s] = (((unsigned)(dst[t] & 511)) << 17) | (unsigned)src[t];
            gposL[s] = base[b] + r;
        }
    }
    __syncthreads();
    for (int s = tid; s < nv; s += 256) ebuf[gposL[s]] = ebufL[s];
}

// ---------------- stage 2: per-bucket degree + local scan -> off, then CSR scatter ----------------

__global__ __launch_bounds__(256) void k_bucket(const unsigned* __restrict__ ebuf, const int* __restrict__ bbase,
                                                int* __restrict__ off, int* __restrict__ srcs, int N) {
    __shared__ int degL[512];
    __shared__ int s2[256];
    int b = blockIdx.x;
    int n0 = b << 9;
    int nn = min(512, N - n0);
    int tid = threadIdx.x;
    for (int i = tid; i < nn; i += 256) degL[i] = 0;
    __syncthreads();
    int e0 = bbase[b], e1 = bbase[b + 1];
    for (int i = e0 + tid; i < e1; i += 256) atomicAdd(&degL[ebuf[i] >> 17], 1);
    __syncthreads();
    int a0 = (2 * tid < nn) ? degL[2 * tid] : 0;
    int a1 = (2 * tid + 1 < nn) ? degL[2 * tid + 1] : 0;
    int ps = a0 + a1;
    s2[tid] = ps;
    __syncthreads();
    for (int st = 1; st < 256; st <<= 1) {
        int t = (tid >= st) ? s2[tid - st] : 0;
        __syncthreads();
        s2[tid] += t;
        __syncthreads();
    }
    int excl = s2[tid] - ps;
    if (2 * tid < nn) { off[n0 + 2 * tid] = e0 + excl; degL[2 * tid] = e0 + excl; }
    if (2 * tid + 1 < nn) { off[n0 + 2 * tid + 1] = e0 + excl + a0; degL[2 * tid + 1] = e0 + excl + a0; }
    if (b == NBKT - 1 && tid == 0) off[N] = e1;
    __syncthreads();
    for (int i = e0 + tid; i < e1; i += 256) {
        unsigned p = ebuf[i];
        int dl = (int)(p >> 17);
        int pos = atomicAdd(&degL[dl], 1);
        srcs[pos] = (int)(p & 0x1FFFFu);
    }
}

// ---------------- weight pre-pack (fp16 single, all 6 matrices) ----------------

struct W6 { const float* w[6]; };

__global__ __launch_bounds__(256) void k_packw6(W6 ws6, ushort* __restrict__ pk) {
    int m = blockIdx.x >> 6;
    int p = (blockIdx.x & 63) * 256 + threadIdx.x;   // 0..16383
    const float* W = ws6.w[m];
    ushort* o = pk + (size_t)m * 16384;
    int j = p & 7, l = (p >> 3) & 63, n = (p >> 9) & 7, kc = p >> 12;
    int row = kc * 32 + ((l >> 4) & 3) * 8 + j;
    int col = n * 16 + (l & 15);
    union { _Float16 h; ushort u; } cv;
    cv.h = (_Float16)W[row * 128 + col];
    o[p] = cv.u;
}

// ---------------- fused GIN layer: gather-sum -> LDS -> GEMM1+ReLU -> LDS -> GEMM2 + stats ----------------
// wave owns 32 rows + a private 8 KB LDS tile. Phase A: each 16-lane group aggregates one node
// (8 groups sequentially), fp32 acc -> fp16 into swizzled LDS. No barriers needed between
// phases (same-wave DS ops are in-order); only the cross-wave stats overlay keeps barriers.

__global__ __launch_bounds__(256, 4) void k_gin(const __half* __restrict__ Xh, __half* __restrict__ out,
        const int* __restrict__ off, const int* __restrict__ srcs,
        const ushort* __restrict__ pk1, const float* __restrict__ b1,
        const ushort* __restrict__ pk2, const float* __restrict__ b2,
        float* __restrict__ stats, int N) {
    __shared__ _Float16 tile[4 * 32 * 128];   // 32 KB
    int tid = threadIdx.x;
    int wid = tid >> 6, l = tid & 63;
    int lr = l & 15, lg = l >> 4;
    int r0 = blockIdx.x * 128 + wid * 32;
    int wbase = wid * 32 * 128;

    const uint4* X16 = (const uint4*)Xh;   // one uint4 = 8 halves; row = 16 uint4
    union U { uint4 u4; __half2 h[4]; };

    // ---- Phase A: gather 32 rows (8 passes of 4 nodes; lg = node-in-pass, lr = chunk) ----
    for (int g = 0; g < 8; ++g) {
        int row = g * 4 + lg;
        int node = r0 + row;
        float2 acc[4];
        if (node < N) {
            U r; r.u4 = X16[(size_t)node * 16 + lr];
#pragma unroll
            for (int k = 0; k < 4; ++k) acc[k] = __half22float2(r.h[k]);
            int s = off[node], e = off[node + 1];
            int j = s;
            for (; j + 7 < e; j += 8) {
                int u0 = srcs[j], u1 = srcs[j + 1], u2 = srcs[j + 2], u3 = srcs[j + 3];
                int u4 = srcs[j + 4], u5 = srcs[j + 5], u6 = srcs[j + 6], u7 = srcs[j + 7];
                U r0_, r1_, r2_, r3_, r4_, r5_, r6_, r7_;
                r0_.u4 = X16[(size_t)u0 * 16 + lr];
                r1_.u4 = X16[(size_t)u1 * 16 + lr];
                r2_.u4 = X16[(size_t)u2 * 16 + lr];
                r3_.u4 = X16[(size_t)u3 * 16 + lr];
                r4_.u4 = X16[(size_t)u4 * 16 + lr];
                r5_.u4 = X16[(size_t)u5 * 16 + lr];
                r6_.u4 = X16[(size_t)u6 * 16 + lr];
                r7_.u4 = X16[(size_t)u7 * 16 + lr];
#pragma unroll
                for (int k = 0; k < 4; ++k) {
                    float2 f0 = __half22float2(r0_.h[k]), f1 = __half22float2(r1_.h[k]);
                    float2 f2 = __half22float2(r2_.h[k]), f3 = __half22float2(r3_.h[k]);
                    float2 f4 = __half22float2(r4_.h[k]), f5 = __half22float2(r5_.h[k]);
                    float2 f6 = __half22float2(r6_.h[k]), f7 = __half22float2(r7_.h[k]);
                    acc[k].x += ((f0.x + f1.x) + (f2.x + f3.x)) + ((f4.x + f5.x) + (f6.x + f7.x));
                    acc[k].y += ((f0.y + f1.y) + (f2.y + f3.y)) + ((f4.y + f5.y) + (f6.y + f7.y));
                }
            }
            for (; j < e; ++j) {
                U r2; r2.u4 = X16[(size_t)srcs[j] * 16 + lr];
#pragma unroll
                for (int k = 0; k < 4; ++k) {
                    float2 f = __half22float2(r2.h[k]);
                    acc[k].x += f.x;
                    acc[k].y += f.y;
                }
            }
        } else {
#pragma unroll
            for (int k = 0; k < 4; ++k) acc[k] = make_float2(0.f, 0.f);
        }
        f16x8 v;
#pragma unroll
        for (int k = 0; k < 4; ++k) {
            v[2 * k] = (_Float16)acc[k].x;
            v[2 * k + 1] = (_Float16)acc[k].y;
        }
        *(f16x8*)&tile[wbase + row * 128 + ((lr ^ (row & 15)) << 3)] = v;
    }

    const f16x8* B1 = (const f16x8*)pk1;
    const f16x8* B2 = (const f16x8*)pk2;

    f32x4 acc[2][8];
#pragma unroll
    for (int m = 0; m < 2; ++m)
#pragma unroll
        for (int n = 0; n < 8; ++n) acc[m][n] = (f32x4){0.f, 0.f, 0.f, 0.f};

    // ---- GEMM1 (A from LDS) ----
#pragma unroll
    for (int kc = 0; kc < 4; ++kc) {
        f16x8 af[2];
#pragma unroll
        for (int m = 0; m < 2; ++m) {
            int row = m * 16 + lr;
            af[m] = *(const f16x8*)&tile[wbase + row * 128 + (((kc * 4 + lg) ^ (row & 15)) << 3)];
        }
#pragma unroll
        for (int n = 0; n < 8; ++n) {
            f16x8 bf = B1[(kc * 8 + n) * 64 + l];
#pragma unroll
            for (int m = 0; m < 2; ++m)
                acc[m][n] = __builtin_amdgcn_mfma_f32_16x16x32_f16(af[m], bf, acc[m][n], 0, 0, 0);
        }
    }

    // ---- epilogue1: bias + ReLU, fp16 restage to LDS (same swizzle) ----
#pragma unroll
    for (int n = 0; n < 8; ++n) {
        float bv = b1[n * 16 + lr];
        int col = n * 16 + lr;
        int chunk = col >> 3;
        int lo3 = col & 7;
#pragma unroll
        for (int m = 0; m < 2; ++m) {
#pragma unroll
            for (int i = 0; i < 4; ++i) {
                int row = m * 16 + lg * 4 + i;
                float v = fmaxf(acc[m][n][i] + bv, 0.f);
                tile[wbase + row * 128 + ((chunk ^ (row & 15)) << 3) + lo3] = (_Float16)v;
            }
        }
    }

    // ---- GEMM2 (A from LDS) ----
#pragma unroll
    for (int m = 0; m < 2; ++m)
#pragma unroll
        for (int n = 0; n < 8; ++n) acc[m][n] = (f32x4){0.f, 0.f, 0.f, 0.f};

#pragma unroll
    for (int kc = 0; kc < 4; ++kc) {
        f16x8 af[2];
#pragma unroll
        for (int m = 0; m < 2; ++m) {
            int row = m * 16 + lr;
            af[m] = *(const f16x8*)&tile[wbase + row * 128 + (((kc * 4 + lg) ^ (row & 15)) << 3)];
        }
#pragma unroll
        for (int n = 0; n < 8; ++n) {
            f16x8 bf = B2[(kc * 8 + n) * 64 + l];
#pragma unroll
            for (int m = 0; m < 2; ++m)
                acc[m][n] = __builtin_amdgcn_mfma_f32_16x16x32_f16(af[m], bf, acc[m][n], 0, 0, 0);
        }
    }
    __syncthreads();   // all waves' LDS reads done before cross-wave stats overlay

    // ---- epilogue2: bias, stats, fp16 store ----
    float s1[8], s2[8];
#pragma unroll
    for (int n = 0; n < 8; ++n) { s1[n] = 0.f; s2[n] = 0.f; }

#pragma unroll
    for (int n = 0; n < 8; ++n) {
        float bv = b2[n * 16 + lr];
#pragma unroll
        for (int m = 0; m < 2; ++m) {
#pragma unroll
            for (int i = 0; i < 4; ++i) {
                int r = r0 + m * 16 + lg * 4 + i;
                if (r < N) {
                    float v = acc[m][n][i] + bv;
                    s1[n] += v;
                    s2[n] += v * v;
                    out[(size_t)r * 128 + n * 16 + lr] = __float2half(v);
                }
            }
        }
    }

    float* ls = (float*)tile;   // overlay [4][256] floats = 4 KB
#pragma unroll
    for (int n = 0; n < 8; ++n) {
        float a = s1[n], b = s2[n];
        a += __shfl_xor(a, 16, 64); a += __shfl_xor(a, 32, 64);
        b += __shfl_xor(b, 16, 64); b += __shfl_xor(b, 32, 64);
        if (lg == 0) {
            ls[wid * 256 + n * 16 + lr] = a;
            ls[wid * 256 + 128 + n * 16 + lr] = b;
        }
    }
    __syncthreads();
    float t = ls[tid] + ls[256 + tid] + ls[512 + tid] + ls[768 + tid];
    atomicAdd(&stats[tid], t);
}

// ---------------- BN apply -> h' (fp16) + segmented mean-pool accumulate ----------------
// 256 threads: channel = tid&127, row-half = tid>>7 (32 consecutive rows each)

__global__ __launch_bounds__(256) void k_bnpool(const __half* __restrict__ h, __half* __restrict__ hp,
                                                const float* __restrict__ stats,
                                                const float* __restrict__ gamma, const float* __restrict__ beta,
                                                const int* __restrict__ batch, float* __restrict__ pool,
                                                int loff, int N) {
    int c = threadIdx.x & 127;
    int half = threadIdx.x >> 7;
    const float invN = 1.0f / (float)N;
    float mean = stats[c] * invN;
    float var = stats[128 + c] * invN - mean * mean;
    float rstd = rsqrtf(var + BN_EPS);
    float gsc = gamma[c] * rstd;
    float bs = beta[c] - mean * gsc;

    int r0 = blockIdx.x * 64 + half * 32;
    int r1 = min(r0 + 32, N);
    float acc = 0.f;
    int curg = -1;
    for (int r = r0; r < r1; ++r) {
        float v = __half2float(h[(size_t)r * 128 + c]);
        float hv = fmaxf(fmaf(v, gsc, bs), 0.f);
        hp[(size_t)r * 128 + c] = __float2half(hv);
        int g = batch[r];
        if (g != curg) {
            if (curg >= 0) atomicAdd(&pool[(size_t)curg * 384 + loff + c], acc);
            curg = g;
            acc = hv;
        } else {
            acc += hv;
        }
    }
    if (curg >= 0) atomicAdd(&pool[(size_t)curg * 384 + loff + c], acc);
}

// ---------------- final linear + row L2-normalize ----------------

__global__ __launch_bounds__(128) void k_final(const float* __restrict__ pool, const int* __restrict__ gcnt,
                                               const float* __restrict__ Wl, const float* __restrict__ bl,
                                               float* __restrict__ out) {
    __shared__ float sh[384];
    __shared__ float red[128];
    int g = blockIdx.x;
    int tid = threadIdx.x;
    float inv = 1.0f / fmaxf((float)gcnt[g], 1.0f);
    for (int t = tid; t < 384; t += 128) sh[t] = pool[(size_t)g * 384 + t] * inv;
    __syncthreads();
    float acc = bl[tid];
    for (int k = 0; k < 384; ++k) acc = fmaf(sh[k], Wl[(size_t)k * 128 + tid], acc);
    red[tid] = acc * acc;
    __syncthreads();
    for (int s = 64; s > 0; s >>= 1) {
        if (tid < s) red[tid] += red[tid + s];
        __syncthreads();
    }
    float norm = sqrtf(red[0]);
    float scale = 1.0f / fmaxf(norm, 1e-12f);
    out[(size_t)g * 128 + tid] = acc * scale;
}

// ---------------- host ----------------

extern "C" void kernel_launch(void* const* d_in, const int* in_sizes, int n_in,
                              void* d_out, int out_size, void* d_ws, size_t ws_size,
                              hipStream_t stream) {
    const float* x = (const float*)d_in[0];
    const int* edge_index = (const int*)d_in[1];
    const int* batch = (const int*)d_in[2];
    const float* Wa[3] = {(const float*)d_in[3], (const float*)d_in[9], (const float*)d_in[15]};
    const float* ba[3] = {(const float*)d_in[4], (const float*)d_in[10], (const float*)d_in[16]};
    const float* Wb[3] = {(const float*)d_in[5], (const float*)d_in[11], (const float*)d_in[17]};
    const float* bb[3] = {(const float*)d_in[6], (const float*)d_in[12], (const float*)d_in[18]};
    const float* gm[3] = {(const float*)d_in[7], (const float*)d_in[13], (const float*)d_in[19]};
    const float* be[3] = {(const float*)d_in[8], (const float*)d_in[14], (const float*)d_in[20]};
    const float* Wl = (const float*)d_in[21];
    const float* bl = (const float*)d_in[22];
    float* out = (float*)d_out;

    const int N = N_NODES, E = N_EDGES, G = N_GRAPHS;
    const int* e_src = edge_index;
    const int* e_dst = edge_index + E;

    char* ws = (char*)d_ws;
    size_t o = 0;
    auto alloc = [&](size_t bytes) -> char* {
        char* p = ws + o;
        o = (o + bytes + 255) & ~(size_t)255;
        return p;
    };
    int* off = (int*)alloc((size_t)(N + 1) * 4);
    int* srcs = (int*)alloc((size_t)E * 4);
    int* gcnt = (int*)alloc((size_t)G * 4);
    int* bcnt = (int*)alloc(256 * 4);
    int* bbase = (int*)alloc(256 * 4);
    int* gcur = (int*)alloc(256 * 4);
    float* stats = (float*)alloc(3 * 256 * 4);
    ushort* wpk = (ushort*)alloc(6 * 16384 * 2);            // fp16 packed weights
    float* pool = (float*)alloc((size_t)G * 384 * 4);
    __half* B0 = (__half*)alloc((size_t)N * 128 * 2);       // x16, then h'_l (layer input)
    __half* B1 = (__half*)alloc((size_t)N * 128 * 2);       // raw h_l (layer output)
    unsigned* ebuf = (unsigned*)B1;  // ebuf dead before B1's first write (layer-0 k_gin)
    (void)ws_size;

    hipMemsetAsync(bcnt, 0, 256 * 4, stream);
    hipMemsetAsync(stats, 0, 3 * 256 * 4, stream);
    hipMemsetAsync(pool, 0, (size_t)G * 384 * 4, stream);

    const int E4 = E / 4;

    k_bcnt<<<256, 256, 0, stream>>>((const int4*)e_dst, bcnt, E4);
    k_bscan<<<1, 256, 0, stream>>>(bcnt, bbase, gcur);
    k_gstart<<<2, 256, 0, stream>>>(batch, gcnt, N);
    k_part<<<(E + PART_CHUNK - 1) / PART_CHUNK, 256, 0, stream>>>(e_src, e_dst, gcur, ebuf, E);
    k_bucket<<<NBKT, 256, 0, stream>>>(ebuf, bbase, off, srcs, N);

    const int n8 = N * 128 / 8;
    k_x2h<<<(n8 + 255) / 256, 256, 0, stream>>>((const float4*)x, (uint4*)B0, n8);

    W6 w6;
    w6.w[0] = Wa[0]; w6.w[1] = Wb[0]; w6.w[2] = Wa[1];
    w6.w[3] = Wb[1]; w6.w[4] = Wa[2]; w6.w[5] = Wb[2];
    k_packw6<<<384, 256, 0, stream>>>(w6, wpk);

    const int ginBlocks = (N + 127) / 128;
    const int bnBlocks = (N + 63) / 64;

    for (int l = 0; l < 3; ++l) {
        float* statsl = stats + l * 256;
        k_gin<<<ginBlocks, 256, 0, stream>>>(B0, B1, off, srcs,
                                             wpk + (size_t)(2 * l) * 16384, ba[l],
                                             wpk + (size_t)(2 * l + 1) * 16384, bb[l], statsl, N);
        k_bnpool<<<bnBlocks, 256, 0, stream>>>(B1, B0, statsl, gm[l], be[l], batch, pool, l * 128, N);
    }

    k_final<<<G, 128, 0, stream>>>(pool, gcnt, Wl, bl, out);
}